// Round 1
// baseline (985.842 us; speedup 1.0000x reference)
//
#include <hip/hip_runtime.h>

// Problem: b=32, n=512, dim=512, H=8, Dh=64, cols(QKV)=1536, MAX_POS=512
// ws layout (floats): Q [256][512][64] | K^T [256][64][512] | V [256][512][64] | O [16384][512]
static constexpr size_t QOFF = 0;
static constexpr size_t KOFF = 8388608;
static constexpr size_t VOFF = 16777216;
static constexpr size_t OOFF = 25165824;

// ---------------------------------------------------------------------------
// Kernel 1: qkv = X[16384x512] @ W[512x1536], scattered to Q / K^T / V
// 128x128 tile, BK=8, 8x8 micro-tile per thread, 256 threads.
// ---------------------------------------------------------------------------
__global__ __launch_bounds__(256) void qkv_gemm(const float* __restrict__ X,
                                                const float* __restrict__ W,
                                                float* __restrict__ ws) {
  __shared__ __align__(16) float As[8 * 132];  // [k][m], pad stride 132
  __shared__ __align__(16) float Bs[8 * 132];  // [k][g*64 + txc*4 + u]
  const int tid = threadIdx.x;
  const int tx = tid & 15, ty = tid >> 4;
  const int m0 = blockIdx.x * 128;
  const int bn = blockIdx.y;
  const int c0 = bn * 128;

  float acc[8][8];
#pragma unroll
  for (int v = 0; v < 8; ++v)
#pragma unroll
    for (int u = 0; u < 8; ++u) acc[v][u] = 0.f;

  const int mA = tid >> 1;
  const int k4A = (tid & 1) * 4;
  const int t32 = tid & 31;
  const int kB = tid >> 5;
  const int gB = t32 & 1;
  const int txcB = t32 >> 1;

  for (int kk = 0; kk < 512; kk += 8) {
    __syncthreads();
    float4 a = *(const float4*)(X + (size_t)(m0 + mA) * 512 + kk + k4A);
    As[(k4A + 0) * 132 + mA] = a.x;
    As[(k4A + 1) * 132 + mA] = a.y;
    As[(k4A + 2) * 132 + mA] = a.z;
    As[(k4A + 3) * 132 + mA] = a.w;
    *(float4*)(Bs + kB * 132 + gB * 64 + txcB * 4) =
        *(const float4*)(W + (size_t)(kk + kB) * 1536 + c0 + t32 * 4);
    __syncthreads();
#pragma unroll
    for (int k = 0; k < 8; ++k) {
      float4 a0 = *(const float4*)(As + k * 132 + ty * 8);
      float4 a1 = *(const float4*)(As + k * 132 + ty * 8 + 4);
      float4 b0 = *(const float4*)(Bs + k * 132 + tx * 4);        // cols 8tx..+3
      float4 b1 = *(const float4*)(Bs + k * 132 + 64 + tx * 4);   // cols 8tx+4..+7
      float av[8] = {a0.x, a0.y, a0.z, a0.w, a1.x, a1.y, a1.z, a1.w};
      float bv[8] = {b0.x, b0.y, b0.z, b0.w, b1.x, b1.y, b1.z, b1.w};
#pragma unroll
      for (int v = 0; v < 8; ++v)
#pragma unroll
        for (int u = 0; u < 8; ++u) acc[v][u] = fmaf(av[v], bv[u], acc[v][u]);
    }
  }

  // Epilogue: block covers exactly one of {Q,K,V} (bn>>2) and 2 heads.
  const int which = bn >> 2;
  const int h = (bn & 3) * 2 + (tx >> 3);
  const int d0 = (tx & 7) * 8;
  const int b = m0 >> 9;
  const int nr0 = (m0 & 511) + ty * 8;
  const int bh = b * 8 + h;
  float* base = ws + (which == 1 ? KOFF : (which == 2 ? VOFF : QOFF)) + (size_t)bh * 32768;
  if (which == 1) {  // K stored transposed: [d][n]
#pragma unroll
    for (int u = 0; u < 8; ++u) {
      *(float4*)(base + (d0 + u) * 512 + nr0) =
          make_float4(acc[0][u], acc[1][u], acc[2][u], acc[3][u]);
      *(float4*)(base + (d0 + u) * 512 + nr0 + 4) =
          make_float4(acc[4][u], acc[5][u], acc[6][u], acc[7][u]);
    }
  } else {  // Q, V natural: [n][d]
#pragma unroll
    for (int v = 0; v < 8; ++v) {
      *(float4*)(base + (size_t)(nr0 + v) * 64 + d0) =
          make_float4(acc[v][0], acc[v][1], acc[v][2], acc[v][3]);
      *(float4*)(base + (size_t)(nr0 + v) * 64 + d0 + 4) =
          make_float4(acc[v][4], acc[v][5], acc[v][6], acc[v][7]);
    }
  }
}

// ---------------------------------------------------------------------------
// Kernel 2: fused attention with relative-position bias + online softmax.
// Block = (64 query rows of one bh), 256 threads, 4x4 register tiles.
// logit(i,j) = (scale*log2e) * q_i . (k_j + rel_table[i-j+512])
// ---------------------------------------------------------------------------
__global__ __launch_bounds__(256) void attn_fused(const float* __restrict__ ws_in,
                                                  float* __restrict__ ws,
                                                  const float* __restrict__ rel) {
  __shared__ __align__(16) float Qt[64 * 64];    // [i][d], pre-scaled
  __shared__ __align__(16) float KtPs[64 * 64];  // Kt [d][j]; later Ps [j][i^swz]
  __shared__ __align__(16) float Vs[64 * 64];    // [j][d]
  __shared__ __align__(16) float Tt[32 * 128];   // [dh][dloc], half of d at a time

  const int tid = threadIdx.x;
  const int tx = tid & 15, ty = tid >> 4;
  const int i0 = blockIdx.x * 64;
  const int bh = blockIdx.y;

  const float* Q = ws_in + QOFF + (size_t)bh * 32768;
  const float* Kg = ws_in + KOFF + (size_t)bh * 32768;  // [d][n]
  const float* Vg = ws_in + VOFF + (size_t)bh * 32768;  // [n][d]

  constexpr float SCL = 0.125f * 1.44269504088896340736f;  // scale * log2(e)

  // Stage Q tile (pre-scaled)
#pragma unroll
  for (int p = 0; p < 4; ++p) {
    int i = (tid >> 4) + p * 16;
    int d0 = (tid & 15) * 4;
    float4 q = *(const float4*)(Q + (size_t)(i0 + i) * 64 + d0);
    *(float4*)(Qt + i * 64 + d0) = make_float4(q.x * SCL, q.y * SCL, q.z * SCL, q.w * SCL);
  }

  float m_i[4] = {-1e30f, -1e30f, -1e30f, -1e30f};
  float l_i[4] = {0.f, 0.f, 0.f, 0.f};
  float o[4][4];
#pragma unroll
  for (int v = 0; v < 4; ++v)
#pragma unroll
    for (int u = 0; u < 4; ++u) o[v][u] = 0.f;

  for (int jc = 0; jc < 8; ++jc) {
    const int j0 = jc * 64;
    __syncthreads();  // prior PV reads of KtPs/Vs done
    // Stage Kt [d][j] and Vs [j][d]
#pragma unroll
    for (int p = 0; p < 4; ++p) {
      int r = (tid >> 4) + p * 16;
      int c4 = (tid & 15) * 4;
      *(float4*)(KtPs + r * 64 + c4) = *(const float4*)(Kg + (size_t)r * 512 + j0 + c4);
      *(float4*)(Vs + r * 64 + c4) = *(const float4*)(Vg + (size_t)(j0 + r) * 64 + c4);
    }
    const int dbase = i0 - j0 + 449;  // delta = i-j+512 = dbase + dloc, dloc in [0,128)
    float s[4][4];
#pragma unroll
    for (int v = 0; v < 4; ++v)
#pragma unroll
      for (int u = 0; u < 4; ++u) s[v][u] = 0.f;

#pragma unroll
    for (int hf = 0; hf < 2; ++hf) {
      if (hf) __syncthreads();  // Tt half-0 reads done
      // Stage Tt for d in [hf*32, hf*32+32)
#pragma unroll
      for (int p = 0; p < 4; ++p) {
        int e = tid + 256 * p;  // 0..1023 float4 units
        int dl = e & 127;
        int dh0 = (e >> 7) << 2;  // 0,4,...,28
        float4 t = *(const float4*)(rel + (size_t)(dbase + dl) * 64 + hf * 32 + dh0);
        Tt[(dh0 + 0) * 128 + dl] = t.x;
        Tt[(dh0 + 1) * 128 + dl] = t.y;
        Tt[(dh0 + 2) * 128 + dl] = t.z;
        Tt[(dh0 + 3) * 128 + dl] = t.w;
      }
      __syncthreads();  // staging visible
      const int w0 = 4 * (ty - tx) + 60;  // 4-aligned, in [0,120]
#pragma unroll 4
      for (int dh = 0; dh < 32; ++dh) {
        const int d = hf * 32 + dh;
        float4 kq = *(const float4*)(KtPs + d * 64 + tx * 4);
        float4 ta = *(const float4*)(Tt + dh * 128 + w0);
        float4 tb = *(const float4*)(Tt + dh * 128 + w0 + 4);
        float kk4[4] = {kq.x, kq.y, kq.z, kq.w};
        float tw[8] = {ta.x, ta.y, ta.z, ta.w, tb.x, tb.y, tb.z, tb.w};
        float qv[4];
#pragma unroll
        for (int v = 0; v < 4; ++v) qv[v] = Qt[(ty * 4 + v) * 64 + d];
#pragma unroll
        for (int v = 0; v < 4; ++v)
#pragma unroll
          for (int u = 0; u < 4; ++u) {
            s[v][u] = fmaf(qv[v], kk4[u], s[v][u]);
            s[v][u] = fmaf(qv[v], tw[3 + v - u], s[v][u]);
          }
      }
    }

    // Online softmax update (base-2), 16-lane row groups
    float mc[4];
#pragma unroll
    for (int v = 0; v < 4; ++v)
      mc[v] = fmaxf(fmaxf(s[v][0], s[v][1]), fmaxf(s[v][2], s[v][3]));
#pragma unroll
    for (int msk = 1; msk < 16; msk <<= 1)
#pragma unroll
      for (int v = 0; v < 4; ++v) mc[v] = fmaxf(mc[v], __shfl_xor(mc[v], msk));
#pragma unroll
    for (int v = 0; v < 4; ++v) {
      float mn = fmaxf(m_i[v], mc[v]);
      float al = exp2f(m_i[v] - mn);
      m_i[v] = mn;
      float ls = 0.f;
#pragma unroll
      for (int u = 0; u < 4; ++u) {
        s[v][u] = exp2f(s[v][u] - mn);
        ls += s[v][u];
      }
#pragma unroll
      for (int msk = 1; msk < 16; msk <<= 1) ls += __shfl_xor(ls, msk);
      l_i[v] = l_i[v] * al + ls;
#pragma unroll
      for (int u = 0; u < 4; ++u) o[v][u] *= al;
    }

    __syncthreads();  // all Kt reads done; reuse as Ps
    // Ps[j][i] with XOR column swizzle (key = j>>2) to avoid write conflicts
#pragma unroll
    for (int u = 0; u < 4; ++u) {
      int j = tx * 4 + u;
      int col = (ty * 4) ^ (((j >> 2) & 15) << 2);
      *(float4*)(KtPs + j * 64 + col) = make_float4(s[0][u], s[1][u], s[2][u], s[3][u]);
    }
    __syncthreads();  // Ps ready
    // PV accumulate
#pragma unroll 4
    for (int j = 0; j < 64; ++j) {
      int col = (ty * 4) ^ (((j >> 2) & 15) << 2);
      float4 p4 = *(const float4*)(KtPs + j * 64 + col);
      float4 v4 = *(const float4*)(Vs + j * 64 + tx * 4);
      float pa[4] = {p4.x, p4.y, p4.z, p4.w};
      float va[4] = {v4.x, v4.y, v4.z, v4.w};
#pragma unroll
      for (int v = 0; v < 4; ++v)
#pragma unroll
        for (int u = 0; u < 4; ++u) o[v][u] = fmaf(pa[v], va[u], o[v][u]);
    }
  }

  // Write O in [b][n][h*64+d] layout for the final GEMM
  const int b = bh >> 3, h = bh & 7;
  float* Og = ws + OOFF;
#pragma unroll
  for (int v = 0; v < 4; ++v) {
    float inv = 1.0f / l_i[v];
    size_t addr = ((size_t)(b * 512 + i0 + ty * 4 + v)) * 512 + h * 64 + tx * 4;
    *(float4*)(Og + addr) =
        make_float4(o[v][0] * inv, o[v][1] * inv, o[v][2] * inv, o[v][3] * inv);
  }
}

// ---------------------------------------------------------------------------
// Kernel 3: out = O[16384x512] @ W_out[512x512] + b_out
// ---------------------------------------------------------------------------
__global__ __launch_bounds__(256) void out_gemm(const float* __restrict__ ws,
                                                const float* __restrict__ W,
                                                const float* __restrict__ bias,
                                                float* __restrict__ out) {
  const float* A = ws + OOFF;
  __shared__ __align__(16) float As[8 * 132];
  __shared__ __align__(16) float Bs[8 * 132];
  const int tid = threadIdx.x;
  const int tx = tid & 15, ty = tid >> 4;
  const int m0 = blockIdx.x * 128;
  const int c0 = blockIdx.y * 128;

  float acc[8][8];
#pragma unroll
  for (int v = 0; v < 8; ++v)
#pragma unroll
    for (int u = 0; u < 8; ++u) acc[v][u] = 0.f;

  const int mA = tid >> 1;
  const int k4A = (tid & 1) * 4;
  const int t32 = tid & 31;
  const int kB = tid >> 5;
  const int gB = t32 & 1;
  const int txcB = t32 >> 1;

  for (int kk = 0; kk < 512; kk += 8) {
    __syncthreads();
    float4 a = *(const float4*)(A + (size_t)(m0 + mA) * 512 + kk + k4A);
    As[(k4A + 0) * 132 + mA] = a.x;
    As[(k4A + 1) * 132 + mA] = a.y;
    As[(k4A + 2) * 132 + mA] = a.z;
    As[(k4A + 3) * 132 + mA] = a.w;
    *(float4*)(Bs + kB * 132 + gB * 64 + txcB * 4) =
        *(const float4*)(W + (size_t)(kk + kB) * 512 + c0 + t32 * 4);
    __syncthreads();
#pragma unroll
    for (int k = 0; k < 8; ++k) {
      float4 a0 = *(const float4*)(As + k * 132 + ty * 8);
      float4 a1 = *(const float4*)(As + k * 132 + ty * 8 + 4);
      float4 b0 = *(const float4*)(Bs + k * 132 + tx * 4);
      float4 b1 = *(const float4*)(Bs + k * 132 + 64 + tx * 4);
      float av[8] = {a0.x, a0.y, a0.z, a0.w, a1.x, a1.y, a1.z, a1.w};
      float bv[8] = {b0.x, b0.y, b0.z, b0.w, b1.x, b1.y, b1.z, b1.w};
#pragma unroll
      for (int v = 0; v < 8; ++v)
#pragma unroll
        for (int u = 0; u < 8; ++u) acc[v][u] = fmaf(av[v], bv[u], acc[v][u]);
    }
  }

  const int cc = c0 + tx * 8;
  float4 bb0 = *(const float4*)(bias + cc);
  float4 bb1 = *(const float4*)(bias + cc + 4);
#pragma unroll
  for (int v = 0; v < 8; ++v) {
    int m = m0 + ty * 8 + v;
    *(float4*)(out + (size_t)m * 512 + cc) =
        make_float4(acc[v][0] + bb0.x, acc[v][1] + bb0.y, acc[v][2] + bb0.z, acc[v][3] + bb0.w);
    *(float4*)(out + (size_t)m * 512 + cc + 4) =
        make_float4(acc[v][4] + bb1.x, acc[v][5] + bb1.y, acc[v][6] + bb1.z, acc[v][7] + bb1.w);
  }
}

// ---------------------------------------------------------------------------
extern "C" void kernel_launch(void* const* d_in, const int* in_sizes, int n_in,
                              void* d_out, int out_size, void* d_ws, size_t ws_size,
                              hipStream_t stream) {
  const float* x = (const float*)d_in[0];      // [32,512,512]
  const float* Wqkv = (const float*)d_in[1];   // [512,1536]
  const float* rel = (const float*)d_in[2];    // [1025,64]
  const float* Wout = (const float*)d_in[3];   // [512,512]
  const float* bout = (const float*)d_in[4];   // [512]
  float* out = (float*)d_out;
  float* ws = (float*)d_ws;  // needs 33554432 floats = 134.2 MB

  qkv_gemm<<<dim3(128, 12), 256, 0, stream>>>(x, Wqkv, ws);
  attn_fused<<<dim3(8, 256), 256, 0, stream>>>(ws, ws, rel);
  out_gemm<<<dim3(128, 4), 256, 0, stream>>>(ws, Wout, bout, out);
}

// Round 2
// 629.827 us; speedup vs baseline: 1.5653x; 1.5653x over previous
//
#include <hip/hip_runtime.h>

typedef __attribute__((ext_vector_type(8))) short short8;
typedef __attribute__((ext_vector_type(4))) float floatx4;

// ws layout, ushort element offsets: Q(bf16,scaled) | K(bf16) | V^T(bf16) | rel(bf16) | O(fp32)
static constexpr size_t QOFF = 0;           // [256][512][64] bf16
static constexpr size_t KOFF = 8388608;     // [256][512][64] bf16
static constexpr size_t VTOFF = 16777216;   // [256][64][512] bf16
static constexpr size_t RBOFF = 25165824;   // [1025][64] bf16
static constexpr size_t OFLOAT = 12615936;  // float offset (byte 50463744), O [16384][512] fp32

__device__ inline unsigned short f2b(float f) {  // RNE fp32->bf16
  unsigned int u = __float_as_uint(f);
  u += 0x7fffu + ((u >> 16) & 1u);
  return (unsigned short)(u >> 16);
}
__device__ inline float b2f(unsigned short h) {
  return __uint_as_float(((unsigned int)h) << 16);
}

// ---------------------------------------------------------------------------
// Kernel 0: convert rel_table to bf16 in ws
// ---------------------------------------------------------------------------
__global__ void rel_cvt(const float* __restrict__ rel, unsigned short* __restrict__ dst) {
  int i = blockIdx.x * 256 + threadIdx.x;
  if (i < 65600) dst[i] = f2b(rel[i]);
}

// ---------------------------------------------------------------------------
// Kernel 1: qkv = X[16384x512] @ W[512x1536] (fp32 math), bf16 epilogue:
// Q scaled by scale*log2e, natural [n][d]; K natural [n][d]; V transposed [d][n].
// ---------------------------------------------------------------------------
__global__ __launch_bounds__(256) void qkv_gemm(const float* __restrict__ X,
                                                const float* __restrict__ W,
                                                unsigned short* __restrict__ wsb) {
  __shared__ __align__(16) float As[8 * 132];
  __shared__ __align__(16) float Bs[8 * 132];
  const int tid = threadIdx.x;
  const int tx = tid & 15, ty = tid >> 4;
  const int m0 = blockIdx.x * 128;
  const int bn = blockIdx.y;
  const int c0 = bn * 128;

  float acc[8][8];
#pragma unroll
  for (int v = 0; v < 8; ++v)
#pragma unroll
    for (int u = 0; u < 8; ++u) acc[v][u] = 0.f;

  const int mA = tid >> 1;
  const int k4A = (tid & 1) * 4;
  const int t32 = tid & 31;
  const int kB = tid >> 5;
  const int gB = t32 & 1;
  const int txcB = t32 >> 1;

  for (int kk = 0; kk < 512; kk += 8) {
    __syncthreads();
    float4 a = *(const float4*)(X + (size_t)(m0 + mA) * 512 + kk + k4A);
    As[(k4A + 0) * 132 + mA] = a.x;
    As[(k4A + 1) * 132 + mA] = a.y;
    As[(k4A + 2) * 132 + mA] = a.z;
    As[(k4A + 3) * 132 + mA] = a.w;
    *(float4*)(Bs + kB * 132 + gB * 64 + txcB * 4) =
        *(const float4*)(W + (size_t)(kk + kB) * 1536 + c0 + t32 * 4);
    __syncthreads();
#pragma unroll
    for (int k = 0; k < 8; ++k) {
      float4 a0 = *(const float4*)(As + k * 132 + ty * 8);
      float4 a1 = *(const float4*)(As + k * 132 + ty * 8 + 4);
      float4 b0 = *(const float4*)(Bs + k * 132 + tx * 4);
      float4 b1 = *(const float4*)(Bs + k * 132 + 64 + tx * 4);
      float av[8] = {a0.x, a0.y, a0.z, a0.w, a1.x, a1.y, a1.z, a1.w};
      float bv[8] = {b0.x, b0.y, b0.z, b0.w, b1.x, b1.y, b1.z, b1.w};
#pragma unroll
      for (int v = 0; v < 8; ++v)
#pragma unroll
        for (int u = 0; u < 8; ++u) acc[v][u] = fmaf(av[v], bv[u], acc[v][u]);
    }
  }

  const int which = bn >> 2;                 // 0=Q 1=K 2=V
  const int h = (bn & 3) * 2 + (tx >> 3);
  const int d0 = (tx & 7) * 8;
  const int b = m0 >> 9;
  const int nr0 = (m0 & 511) + ty * 8;
  const int bh = b * 8 + h;
  constexpr float SCL = 0.125f * 1.44269504088896340736f;  // scale * log2(e)

  if (which == 2) {  // V^T [d][n]
    unsigned short* base = wsb + VTOFF + (size_t)bh * 32768;
#pragma unroll
    for (int u = 0; u < 8; ++u) {
      unsigned short t[8];
#pragma unroll
      for (int v = 0; v < 8; ++v) t[v] = f2b(acc[v][u]);
      *(uint4*)(base + (size_t)(d0 + u) * 512 + nr0) = *(uint4*)t;
    }
  } else {  // Q (scaled) / K natural [n][d]
    unsigned short* base = wsb + (which == 1 ? KOFF : QOFF) + (size_t)bh * 32768;
    const float scl = (which == 0) ? SCL : 1.0f;
#pragma unroll
    for (int v = 0; v < 8; ++v) {
      unsigned short t[8];
#pragma unroll
      for (int u = 0; u < 8; ++u) t[u] = f2b(acc[v][u] * scl);
      *(uint4*)(base + (size_t)(nr0 + v) * 64 + d0) = *(uint4*)t;
    }
  }
}

// ---------------------------------------------------------------------------
// Kernel 2: MFMA flash attention with Toeplitz bias as a second GEMM.
// Block = (bh, 64 q-rows), 256 thr = 4 waves, wave owns a 16-row strip.
// logit = q_scl.k + q_scl.rel[i-j+512] (base-2); online softmax; PV MFMA.
// ---------------------------------------------------------------------------
__global__ __launch_bounds__(256) void attn_mfma(const unsigned short* __restrict__ wsb,
                                                 float* __restrict__ Og) {
  __shared__ __align__(16) unsigned short Qs[64 * 72];
  __shared__ __align__(16) unsigned short Ks[64 * 72];
  __shared__ __align__(16) unsigned short Vt[64 * 72];
  __shared__ __align__(16) unsigned short Ts[128 * 72];
  __shared__ __align__(16) unsigned short Gs[64 * 136];
  __shared__ __align__(16) unsigned short Ps[64 * 72];

  const int tid = threadIdx.x;
  const int w = tid >> 6, lane = tid & 63;
  const int g = lane >> 4, c = lane & 15;
  const int i0 = blockIdx.x * 64, bh = blockIdx.y;

  const unsigned short* Qg = wsb + QOFF + (size_t)bh * 32768 + (size_t)i0 * 64;
  const unsigned short* Kg = wsb + KOFF + (size_t)bh * 32768;
  const unsigned short* Vg = wsb + VTOFF + (size_t)bh * 32768;
  const unsigned short* Rg = wsb + RBOFF;

  // stage Q strip once (64 rows x 64 bf16)
  for (int e = tid; e < 512; e += 256) {
    int r = e >> 3, o = e & 7;
    *(uint4*)(Qs + r * 72 + o * 8) = *(const uint4*)(Qg + r * 64 + o * 8);
  }

  float m_i[4] = {-1e30f, -1e30f, -1e30f, -1e30f};
  float l_i[4] = {0.f, 0.f, 0.f, 0.f};
  floatx4 oa[4];
#pragma unroll
  for (int t = 0; t < 4; ++t) oa[t] = (floatx4){0.f, 0.f, 0.f, 0.f};

  for (int jc = 0; jc < 8; ++jc) {
    const int j0 = jc * 64;
    __syncthreads();  // prior chunk's Ks/Vt/Ts reads done (also covers Qs staging)
    for (int e = tid; e < 512; e += 256) {
      int r = e >> 3, o = e & 7;
      *(uint4*)(Ks + r * 72 + o * 8) = *(const uint4*)(Kg + (size_t)(j0 + r) * 64 + o * 8);
      *(uint4*)(Vt + r * 72 + o * 8) = *(const uint4*)(Vg + (size_t)r * 512 + j0 + o * 8);
    }
    const int dbase = i0 - j0 + 449;  // delta = dbase + dl, dl = iloc - jj + 63 in [0,126]
    for (int e = tid; e < 1024; e += 256) {
      int r = e >> 3, o = e & 7;
      *(uint4*)(Ts + r * 72 + o * 8) = *(const uint4*)(Rg + (size_t)(dbase + r) * 64 + o * 8);
    }
    __syncthreads();

    const int arow = (w * 16 + c) * 72;
    short8 aq0 = *(const short8*)(Qs + arow + g * 8);
    short8 aq1 = *(const short8*)(Qs + arow + 32 + g * 8);

    // G strip = Q_strip @ T^T  -> Gs (wave-private rows, no barrier needed)
#pragma unroll
    for (int dt = 0; dt < 8; ++dt) {
      floatx4 ga = (floatx4){0.f, 0.f, 0.f, 0.f};
      short8 bt0 = *(const short8*)(Ts + (dt * 16 + c) * 72 + g * 8);
      short8 bt1 = *(const short8*)(Ts + (dt * 16 + c) * 72 + 32 + g * 8);
      ga = __builtin_amdgcn_mfma_f32_16x16x32_bf16(aq0, bt0, ga, 0, 0, 0);
      ga = __builtin_amdgcn_mfma_f32_16x16x32_bf16(aq1, bt1, ga, 0, 0, 0);
#pragma unroll
      for (int r = 0; r < 4; ++r)
        Gs[(w * 16 + g * 4 + r) * 136 + dt * 16 + c] = f2b(ga[r]);
    }

    // S strip = Q_strip @ K^T
    floatx4 s4[4];
#pragma unroll
    for (int t = 0; t < 4; ++t) {
      floatx4 sa = (floatx4){0.f, 0.f, 0.f, 0.f};
      short8 bk0 = *(const short8*)(Ks + (t * 16 + c) * 72 + g * 8);
      short8 bk1 = *(const short8*)(Ks + (t * 16 + c) * 72 + 32 + g * 8);
      sa = __builtin_amdgcn_mfma_f32_16x16x32_bf16(aq0, bk0, sa, 0, 0, 0);
      sa = __builtin_amdgcn_mfma_f32_16x16x32_bf16(aq1, bk1, sa, 0, 0, 0);
      s4[t] = sa;
    }
    // add Toeplitz bias via diagonal gather from Gs
#pragma unroll
    for (int t = 0; t < 4; ++t) {
      const int jj = t * 16 + c;
#pragma unroll
      for (int r = 0; r < 4; ++r) {
        const int il = w * 16 + g * 4 + r;
        s4[t][r] += b2f(Gs[il * 136 + (il - jj + 63)]);
      }
    }

    // online softmax (base-2), rows live on 16-lane groups (fixed g, varying c)
#pragma unroll
    for (int r = 0; r < 4; ++r) {
      float mx = fmaxf(fmaxf(s4[0][r], s4[1][r]), fmaxf(s4[2][r], s4[3][r]));
#pragma unroll
      for (int msk = 1; msk < 16; msk <<= 1) mx = fmaxf(mx, __shfl_xor(mx, msk));
      const float mn = fmaxf(m_i[r], mx);
      const float al = exp2f(m_i[r] - mn);
      m_i[r] = mn;
      float ls = 0.f;
#pragma unroll
      for (int t = 0; t < 4; ++t) {
        float p = exp2f(s4[t][r] - mn);
        s4[t][r] = p;
        ls += p;
      }
#pragma unroll
      for (int msk = 1; msk < 16; msk <<= 1) ls += __shfl_xor(ls, msk);
      l_i[r] = l_i[r] * al + ls;
#pragma unroll
      for (int dt = 0; dt < 4; ++dt) oa[dt][r] *= al;
#pragma unroll
      for (int t = 0; t < 4; ++t)
        Ps[(w * 16 + g * 4 + r) * 72 + t * 16 + c] = f2b(s4[t][r]);
    }

    // O_strip += P_strip @ V   (Ps wave-private; Vt block-shared, staged above)
#pragma unroll
    for (int s = 0; s < 2; ++s) {
      short8 ap = *(const short8*)(Ps + arow + s * 32 + g * 8);
#pragma unroll
      for (int dt = 0; dt < 4; ++dt) {
        short8 bv = *(const short8*)(Vt + (dt * 16 + c) * 72 + s * 32 + g * 8);
        oa[dt] = __builtin_amdgcn_mfma_f32_16x16x32_bf16(ap, bv, oa[dt], 0, 0, 0);
      }
    }
  }

  // epilogue: O in [b][n][h*64+d] fp32 for the final GEMM
  const int b = bh >> 3, h = bh & 7;
#pragma unroll
  for (int r = 0; r < 4; ++r) {
    const float inv = 1.0f / l_i[r];
    const int i = i0 + w * 16 + g * 4 + r;
    const size_t rowoff = ((size_t)(b * 512 + i)) * 512 + h * 64;
#pragma unroll
    for (int dt = 0; dt < 4; ++dt) Og[rowoff + dt * 16 + c] = oa[dt][r] * inv;
  }
}

// ---------------------------------------------------------------------------
// Kernel 3: out = O[16384x512] @ W_out[512x512] + b_out (fp32)
// ---------------------------------------------------------------------------
__global__ __launch_bounds__(256) void out_gemm(const float* __restrict__ A,
                                                const float* __restrict__ W,
                                                const float* __restrict__ bias,
                                                float* __restrict__ out) {
  __shared__ __align__(16) float As[8 * 132];
  __shared__ __align__(16) float Bs[8 * 132];
  const int tid = threadIdx.x;
  const int tx = tid & 15, ty = tid >> 4;
  const int m0 = blockIdx.x * 128;
  const int c0 = blockIdx.y * 128;

  float acc[8][8];
#pragma unroll
  for (int v = 0; v < 8; ++v)
#pragma unroll
    for (int u = 0; u < 8; ++u) acc[v][u] = 0.f;

  const int mA = tid >> 1;
  const int k4A = (tid & 1) * 4;
  const int t32 = tid & 31;
  const int kB = tid >> 5;
  const int gB = t32 & 1;
  const int txcB = t32 >> 1;

  for (int kk = 0; kk < 512; kk += 8) {
    __syncthreads();
    float4 a = *(const float4*)(A + (size_t)(m0 + mA) * 512 + kk + k4A);
    As[(k4A + 0) * 132 + mA] = a.x;
    As[(k4A + 1) * 132 + mA] = a.y;
    As[(k4A + 2) * 132 + mA] = a.z;
    As[(k4A + 3) * 132 + mA] = a.w;
    *(float4*)(Bs + kB * 132 + gB * 64 + txcB * 4) =
        *(const float4*)(W + (size_t)(kk + kB) * 512 + c0 + t32 * 4);
    __syncthreads();
#pragma unroll
    for (int k = 0; k < 8; ++k) {
      float4 a0 = *(const float4*)(As + k * 132 + ty * 8);
      float4 a1 = *(const float4*)(As + k * 132 + ty * 8 + 4);
      float4 b0 = *(const float4*)(Bs + k * 132 + tx * 4);
      float4 b1 = *(const float4*)(Bs + k * 132 + 64 + tx * 4);
      float av[8] = {a0.x, a0.y, a0.z, a0.w, a1.x, a1.y, a1.z, a1.w};
      float bv[8] = {b0.x, b0.y, b0.z, b0.w, b1.x, b1.y, b1.z, b1.w};
#pragma unroll
      for (int v = 0; v < 8; ++v)
#pragma unroll
        for (int u = 0; u < 8; ++u) acc[v][u] = fmaf(av[v], bv[u], acc[v][u]);
    }
  }

  const int cc = c0 + tx * 8;
  float4 bb0 = *(const float4*)(bias + cc);
  float4 bb1 = *(const float4*)(bias + cc + 4);
#pragma unroll
  for (int v = 0; v < 8; ++v) {
    int m = m0 + ty * 8 + v;
    *(float4*)(out + (size_t)m * 512 + cc) =
        make_float4(acc[v][0] + bb0.x, acc[v][1] + bb0.y, acc[v][2] + bb0.z, acc[v][3] + bb0.w);
    *(float4*)(out + (size_t)m * 512 + cc + 4) =
        make_float4(acc[v][4] + bb1.x, acc[v][5] + bb1.y, acc[v][6] + bb1.z, acc[v][7] + bb1.w);
  }
}

// ---------------------------------------------------------------------------
extern "C" void kernel_launch(void* const* d_in, const int* in_sizes, int n_in,
                              void* d_out, int out_size, void* d_ws, size_t ws_size,
                              hipStream_t stream) {
  const float* x = (const float*)d_in[0];      // [32,512,512]
  const float* Wqkv = (const float*)d_in[1];   // [512,1536]
  const float* rel = (const float*)d_in[2];    // [1025,64]
  const float* Wout = (const float*)d_in[3];   // [512,512]
  const float* bout = (const float*)d_in[4];   // [512]
  float* out = (float*)d_out;
  unsigned short* wsb = (unsigned short*)d_ws;
  float* wsf = (float*)d_ws;

  rel_cvt<<<257, 256, 0, stream>>>(rel, wsb + RBOFF);
  qkv_gemm<<<dim3(128, 12), 256, 0, stream>>>(x, Wqkv, wsb);
  attn_mfma<<<dim3(8, 256), 256, 0, stream>>>(wsb, wsf + OFLOAT);
  out_gemm<<<dim3(128, 4), 256, 0, stream>>>(wsf + OFLOAT, Wout, bout, out);
}

// Round 3
// 305.156 us; speedup vs baseline: 3.2306x; 2.0640x over previous
//
#include <hip/hip_runtime.h>

typedef __attribute__((ext_vector_type(8))) short short8;
typedef __attribute__((ext_vector_type(4))) float floatx4;

// ws layout (ushort element offsets):
static constexpr size_t QOFF = 0;           // Q bf16 scaled [256][512][64]
static constexpr size_t KOFF = 8388608;     // K bf16 [256][512][64]
static constexpr size_t VTOFF = 16777216;   // V^T bf16 [256][64][512]
static constexpr size_t RBOFF = 25165824;   // rel bf16 [1025][64]
static constexpr size_t XBOFF = 25231424;   // X bf16 [16384][512]
static constexpr size_t WTOFF = 33620032;   // Wqkv^T bf16 [1536][512]
static constexpr size_t WOTOFF = 34406464;  // Wout^T bf16 [512][512]
static constexpr size_t OBOFF = 34668608;   // O bf16 [16384][512]

__device__ inline unsigned short f2b(float f) {  // RNE fp32->bf16
  unsigned int u = __float_as_uint(f);
  u += 0x7fffu + ((u >> 16) & 1u);
  return (unsigned short)(u >> 16);
}
__device__ inline float b2f(unsigned short h) {
  return __uint_as_float(((unsigned int)h) << 16);
}

// ---------------------------------------------------------------------------
// Converters
// ---------------------------------------------------------------------------
__global__ void rel_cvt(const float* __restrict__ rel, unsigned short* __restrict__ dst) {
  int i = blockIdx.x * 256 + threadIdx.x;
  if (i < 65600) dst[i] = f2b(rel[i]);
}

__global__ __launch_bounds__(256) void x_cvt(const float* __restrict__ in,
                                             unsigned short* __restrict__ dst) {
  size_t i8 = ((size_t)blockIdx.x * 256 + threadIdx.x) * 8;
  float4 a = *(const float4*)(in + i8);
  float4 b = *(const float4*)(in + i8 + 4);
  unsigned short t[8] = {f2b(a.x), f2b(a.y), f2b(a.z), f2b(a.w),
                         f2b(b.x), f2b(b.y), f2b(b.z), f2b(b.w)};
  *(uint4*)(dst + i8) = *(uint4*)t;
}

// transpose+convert: in fp32 [R][C] -> out bf16 [C][R]; grid (C/64, R/64)
__global__ __launch_bounds__(256) void t_cvt(const float* __restrict__ in,
                                             unsigned short* __restrict__ out,
                                             int R, int C) {
  __shared__ float T[64 * 65];
  const int tid = threadIdx.x;
  const int c0 = blockIdx.x * 64, r0 = blockIdx.y * 64;
#pragma unroll
  for (int p = 0; p < 4; ++p) {
    int r = (tid >> 4) + p * 16, c4 = (tid & 15) * 4;
    float4 v = *(const float4*)(in + (size_t)(r0 + r) * C + c0 + c4);
    T[r * 65 + c4 + 0] = v.x;
    T[r * 65 + c4 + 1] = v.y;
    T[r * 65 + c4 + 2] = v.z;
    T[r * 65 + c4 + 3] = v.w;
  }
  __syncthreads();
#pragma unroll
  for (int p = 0; p < 4; ++p) {
    int oc = (tid >> 4) + p * 16;   // input col = output row
    int or4 = (tid & 15) * 4;       // input row group
    unsigned short t[4];
#pragma unroll
    for (int j = 0; j < 4; ++j) t[j] = f2b(T[(or4 + j) * 65 + oc]);
    *(uint2*)(out + (size_t)(c0 + oc) * R + r0 + or4) = *(uint2*)t;
  }
}

// ---------------------------------------------------------------------------
// Kernel 1: qkv = Xb[16384x512] @ Wt^T (bf16 MFMA), scatter epilogue to
// Q(scaled)/K natural [n][d] and V^T [d][n] (operand-swapped MFMA for V).
// ---------------------------------------------------------------------------
__global__ __launch_bounds__(256) void qkv_mfma(const unsigned short* __restrict__ Xb,
                                                const unsigned short* __restrict__ Wt,
                                                unsigned short* __restrict__ wsb) {
  __shared__ __align__(16) unsigned short As[128 * 40];
  __shared__ __align__(16) unsigned short Bs[128 * 40];
  const int tid = threadIdx.x;
  const int w = tid >> 6, lane = tid & 63;
  const int g = lane >> 4, c = lane & 15;
  const int m0 = blockIdx.x * 128, n0 = blockIdx.y * 128;
  const int wr = (w >> 1) * 64, wc = (w & 1) * 64;
  const bool vmode = (blockIdx.y >= 8);

  floatx4 acc[4][4];
#pragma unroll
  for (int mi = 0; mi < 4; ++mi)
#pragma unroll
    for (int ni = 0; ni < 4; ++ni) acc[mi][ni] = (floatx4){0.f, 0.f, 0.f, 0.f};

  for (int kk = 0; kk < 512; kk += 32) {
    __syncthreads();
#pragma unroll
    for (int p = 0; p < 2; ++p) {
      int e = tid + 256 * p;
      int r = e >> 2, o = e & 3;
      *(uint4*)(As + r * 40 + o * 8) = *(const uint4*)(Xb + (size_t)(m0 + r) * 512 + kk + o * 8);
      *(uint4*)(Bs + r * 40 + o * 8) = *(const uint4*)(Wt + (size_t)(n0 + r) * 512 + kk + o * 8);
    }
    __syncthreads();
    short8 a[4], b[4];
#pragma unroll
    for (int mi = 0; mi < 4; ++mi) a[mi] = *(const short8*)(As + (wr + mi * 16 + c) * 40 + g * 8);
#pragma unroll
    for (int ni = 0; ni < 4; ++ni) b[ni] = *(const short8*)(Bs + (wc + ni * 16 + c) * 40 + g * 8);
    if (vmode) {
#pragma unroll
      for (int mi = 0; mi < 4; ++mi)
#pragma unroll
        for (int ni = 0; ni < 4; ++ni)
          acc[mi][ni] = __builtin_amdgcn_mfma_f32_16x16x32_bf16(b[ni], a[mi], acc[mi][ni], 0, 0, 0);
    } else {
#pragma unroll
      for (int mi = 0; mi < 4; ++mi)
#pragma unroll
        for (int ni = 0; ni < 4; ++ni)
          acc[mi][ni] = __builtin_amdgcn_mfma_f32_16x16x32_bf16(a[mi], b[ni], acc[mi][ni], 0, 0, 0);
    }
  }

  constexpr float SCL = 0.125f * 1.44269504088896340736f;  // scale*log2e (Q only)
  if (vmode) {
    // D rows = feature (col of qkv), D cols = x-row. V^T store: lane c -> n contiguous.
#pragma unroll
    for (int mi = 0; mi < 4; ++mi) {
      const int xrow = m0 + wr + mi * 16 + c;
      const int bb = xrow >> 9, nn = xrow & 511;
#pragma unroll
      for (int ni = 0; ni < 4; ++ni) {
#pragma unroll
        for (int r = 0; r < 4; ++r) {
          const int C = n0 + wc + ni * 16 + g * 4 + r;  // 1024..1535
          const int col512 = C & 511;
          const int h = col512 >> 6, d = col512 & 63;
          wsb[VTOFF + (size_t)(bb * 8 + h) * 32768 + (size_t)d * 512 + nn] = f2b(acc[mi][ni][r]);
        }
      }
    }
  } else {
    const size_t base = (blockIdx.y >= 4) ? KOFF : QOFF;
    const float scl = (blockIdx.y >= 4) ? 1.0f : SCL;
#pragma unroll
    for (int ni = 0; ni < 4; ++ni) {
      const int C = n0 + wc + ni * 16 + c;
      const int col512 = C & 511;
      const int h = col512 >> 6, d = col512 & 63;
#pragma unroll
      for (int mi = 0; mi < 4; ++mi) {
#pragma unroll
        for (int r = 0; r < 4; ++r) {
          const int xrow = m0 + wr + mi * 16 + g * 4 + r;
          wsb[base + (size_t)((xrow >> 9) * 8 + h) * 32768 + (size_t)(xrow & 511) * 64 + d] =
              f2b(acc[mi][ni][r] * scl);
        }
      }
    }
  }
}

// ---------------------------------------------------------------------------
// Kernel 2: MFMA flash attention (unchanged math), writes O bf16 [16384][512].
// ---------------------------------------------------------------------------
__global__ __launch_bounds__(256) void attn_mfma(const unsigned short* __restrict__ wsb,
                                                 unsigned short* __restrict__ Ob) {
  __shared__ __align__(16) unsigned short Qs[64 * 72];
  __shared__ __align__(16) unsigned short Ks[64 * 72];
  __shared__ __align__(16) unsigned short Vt[64 * 72];
  __shared__ __align__(16) unsigned short Ts[128 * 72];
  __shared__ __align__(16) unsigned short Gs[64 * 136];
  __shared__ __align__(16) unsigned short Ps[64 * 72];

  const int tid = threadIdx.x;
  const int w = tid >> 6, lane = tid & 63;
  const int g = lane >> 4, c = lane & 15;
  const int i0 = blockIdx.x * 64, bh = blockIdx.y;

  const unsigned short* Qg = wsb + QOFF + (size_t)bh * 32768 + (size_t)i0 * 64;
  const unsigned short* Kg = wsb + KOFF + (size_t)bh * 32768;
  const unsigned short* Vg = wsb + VTOFF + (size_t)bh * 32768;
  const unsigned short* Rg = wsb + RBOFF;

  for (int e = tid; e < 512; e += 256) {
    int r = e >> 3, o = e & 7;
    *(uint4*)(Qs + r * 72 + o * 8) = *(const uint4*)(Qg + r * 64 + o * 8);
  }

  float m_i[4] = {-1e30f, -1e30f, -1e30f, -1e30f};
  float l_i[4] = {0.f, 0.f, 0.f, 0.f};
  floatx4 oa[4];
#pragma unroll
  for (int t = 0; t < 4; ++t) oa[t] = (floatx4){0.f, 0.f, 0.f, 0.f};

  for (int jc = 0; jc < 8; ++jc) {
    const int j0 = jc * 64;
    __syncthreads();
    for (int e = tid; e < 512; e += 256) {
      int r = e >> 3, o = e & 7;
      *(uint4*)(Ks + r * 72 + o * 8) = *(const uint4*)(Kg + (size_t)(j0 + r) * 64 + o * 8);
      *(uint4*)(Vt + r * 72 + o * 8) = *(const uint4*)(Vg + (size_t)r * 512 + j0 + o * 8);
    }
    const int dbase = i0 - j0 + 449;
    for (int e = tid; e < 1024; e += 256) {
      int r = e >> 3, o = e & 7;
      *(uint4*)(Ts + r * 72 + o * 8) = *(const uint4*)(Rg + (size_t)(dbase + r) * 64 + o * 8);
    }
    __syncthreads();

    const int arow = (w * 16 + c) * 72;
    short8 aq0 = *(const short8*)(Qs + arow + g * 8);
    short8 aq1 = *(const short8*)(Qs + arow + 32 + g * 8);

#pragma unroll
    for (int dt = 0; dt < 8; ++dt) {
      floatx4 ga = (floatx4){0.f, 0.f, 0.f, 0.f};
      short8 bt0 = *(const short8*)(Ts + (dt * 16 + c) * 72 + g * 8);
      short8 bt1 = *(const short8*)(Ts + (dt * 16 + c) * 72 + 32 + g * 8);
      ga = __builtin_amdgcn_mfma_f32_16x16x32_bf16(aq0, bt0, ga, 0, 0, 0);
      ga = __builtin_amdgcn_mfma_f32_16x16x32_bf16(aq1, bt1, ga, 0, 0, 0);
#pragma unroll
      for (int r = 0; r < 4; ++r)
        Gs[(w * 16 + g * 4 + r) * 136 + dt * 16 + c] = f2b(ga[r]);
    }

    floatx4 s4[4];
#pragma unroll
    for (int t = 0; t < 4; ++t) {
      floatx4 sa = (floatx4){0.f, 0.f, 0.f, 0.f};
      short8 bk0 = *(const short8*)(Ks + (t * 16 + c) * 72 + g * 8);
      short8 bk1 = *(const short8*)(Ks + (t * 16 + c) * 72 + 32 + g * 8);
      sa = __builtin_amdgcn_mfma_f32_16x16x32_bf16(aq0, bk0, sa, 0, 0, 0);
      sa = __builtin_amdgcn_mfma_f32_16x16x32_bf16(aq1, bk1, sa, 0, 0, 0);
      s4[t] = sa;
    }
#pragma unroll
    for (int t = 0; t < 4; ++t) {
      const int jj = t * 16 + c;
#pragma unroll
      for (int r = 0; r < 4; ++r) {
        const int il = w * 16 + g * 4 + r;
        s4[t][r] += b2f(Gs[il * 136 + (il - jj + 63)]);
      }
    }

#pragma unroll
    for (int r = 0; r < 4; ++r) {
      float mx = fmaxf(fmaxf(s4[0][r], s4[1][r]), fmaxf(s4[2][r], s4[3][r]));
#pragma unroll
      for (int msk = 1; msk < 16; msk <<= 1) mx = fmaxf(mx, __shfl_xor(mx, msk));
      const float mn = fmaxf(m_i[r], mx);
      const float al = exp2f(m_i[r] - mn);
      m_i[r] = mn;
      float ls = 0.f;
#pragma unroll
      for (int t = 0; t < 4; ++t) {
        float p = exp2f(s4[t][r] - mn);
        s4[t][r] = p;
        ls += p;
      }
#pragma unroll
      for (int msk = 1; msk < 16; msk <<= 1) ls += __shfl_xor(ls, msk);
      l_i[r] = l_i[r] * al + ls;
#pragma unroll
      for (int dt = 0; dt < 4; ++dt) oa[dt][r] *= al;
#pragma unroll
      for (int t = 0; t < 4; ++t)
        Ps[(w * 16 + g * 4 + r) * 72 + t * 16 + c] = f2b(s4[t][r]);
    }

#pragma unroll
    for (int s = 0; s < 2; ++s) {
      short8 ap = *(const short8*)(Ps + arow + s * 32 + g * 8);
#pragma unroll
      for (int dt = 0; dt < 4; ++dt) {
        short8 bv = *(const short8*)(Vt + (dt * 16 + c) * 72 + s * 32 + g * 8);
        oa[dt] = __builtin_amdgcn_mfma_f32_16x16x32_bf16(ap, bv, oa[dt], 0, 0, 0);
      }
    }
  }

  const int b = bh >> 3, h = bh & 7;
#pragma unroll
  for (int r = 0; r < 4; ++r) {
    const float inv = 1.0f / l_i[r];
    const int i = i0 + w * 16 + g * 4 + r;
    const size_t rowoff = ((size_t)(b * 512 + i)) * 512 + h * 64;
#pragma unroll
    for (int dt = 0; dt < 4; ++dt) Ob[rowoff + dt * 16 + c] = f2b(oa[dt][r] * inv);
  }
}

// ---------------------------------------------------------------------------
// Kernel 3: out = Ob[16384x512] @ WoT^T + bias (bf16 MFMA, fp32 out)
// ---------------------------------------------------------------------------
__global__ __launch_bounds__(256) void out_mfma(const unsigned short* __restrict__ Ab,
                                                const unsigned short* __restrict__ Bt,
                                                const float* __restrict__ bias,
                                                float* __restrict__ out) {
  __shared__ __align__(16) unsigned short As[128 * 40];
  __shared__ __align__(16) unsigned short Bs[128 * 40];
  const int tid = threadIdx.x;
  const int w = tid >> 6, lane = tid & 63;
  const int g = lane >> 4, c = lane & 15;
  const int m0 = blockIdx.x * 128, n0 = blockIdx.y * 128;
  const int wr = (w >> 1) * 64, wc = (w & 1) * 64;

  floatx4 acc[4][4];
#pragma unroll
  for (int mi = 0; mi < 4; ++mi)
#pragma unroll
    for (int ni = 0; ni < 4; ++ni) acc[mi][ni] = (floatx4){0.f, 0.f, 0.f, 0.f};

  for (int kk = 0; kk < 512; kk += 32) {
    __syncthreads();
#pragma unroll
    for (int p = 0; p < 2; ++p) {
      int e = tid + 256 * p;
      int r = e >> 2, o = e & 3;
      *(uint4*)(As + r * 40 + o * 8) = *(const uint4*)(Ab + (size_t)(m0 + r) * 512 + kk + o * 8);
      *(uint4*)(Bs + r * 40 + o * 8) = *(const uint4*)(Bt + (size_t)(n0 + r) * 512 + kk + o * 8);
    }
    __syncthreads();
    short8 a[4], b[4];
#pragma unroll
    for (int mi = 0; mi < 4; ++mi) a[mi] = *(const short8*)(As + (wr + mi * 16 + c) * 40 + g * 8);
#pragma unroll
    for (int ni = 0; ni < 4; ++ni) b[ni] = *(const short8*)(Bs + (wc + ni * 16 + c) * 40 + g * 8);
#pragma unroll
    for (int mi = 0; mi < 4; ++mi)
#pragma unroll
      for (int ni = 0; ni < 4; ++ni)
        acc[mi][ni] = __builtin_amdgcn_mfma_f32_16x16x32_bf16(a[mi], b[ni], acc[mi][ni], 0, 0, 0);
  }

#pragma unroll
  for (int ni = 0; ni < 4; ++ni) {
    const int C = n0 + wc + ni * 16 + c;
    const float bv = bias[C];
#pragma unroll
    for (int mi = 0; mi < 4; ++mi) {
#pragma unroll
      for (int r = 0; r < 4; ++r) {
        const int m = m0 + wr + mi * 16 + g * 4 + r;
        out[(size_t)m * 512 + C] = acc[mi][ni][r] + bv;
      }
    }
  }
}

// ---------------------------------------------------------------------------
extern "C" void kernel_launch(void* const* d_in, const int* in_sizes, int n_in,
                              void* d_out, int out_size, void* d_ws, size_t ws_size,
                              hipStream_t stream) {
  const float* x = (const float*)d_in[0];      // [32,512,512]
  const float* Wqkv = (const float*)d_in[1];   // [512,1536]
  const float* rel = (const float*)d_in[2];    // [1025,64]
  const float* Wout = (const float*)d_in[3];   // [512,512]
  const float* bout = (const float*)d_in[4];   // [512]
  float* out = (float*)d_out;
  unsigned short* wsb = (unsigned short*)d_ws;

  rel_cvt<<<257, 256, 0, stream>>>(rel, wsb + RBOFF);
  x_cvt<<<4096, 256, 0, stream>>>(x, wsb + XBOFF);
  t_cvt<<<dim3(24, 8), 256, 0, stream>>>(Wqkv, wsb + WTOFF, 512, 1536);
  t_cvt<<<dim3(8, 8), 256, 0, stream>>>(Wout, wsb + WOTOFF, 512, 512);
  qkv_mfma<<<dim3(128, 12), 256, 0, stream>>>(wsb + XBOFF, wsb + WTOFF, wsb);
  attn_mfma<<<dim3(8, 256), 256, 0, stream>>>(wsb, wsb + OBOFF);
  out_mfma<<<dim3(128, 4), 256, 0, stream>>>(wsb + OBOFF, wsb + WOTOFF, bout, out);
}

// Round 4
// 305.140 us; speedup vs baseline: 3.2308x; 1.0001x over previous
//
#include <hip/hip_runtime.h>

typedef __attribute__((ext_vector_type(8))) short short8;
typedef __attribute__((ext_vector_type(4))) float floatx4;

// ws layout (ushort element offsets):
static constexpr size_t QOFF = 0;           // Q bf16 scaled [256][512][64]
static constexpr size_t KOFF = 8388608;     // K bf16 [256][512][64]
static constexpr size_t VTOFF = 16777216;   // V^T bf16 [256][64][512]
static constexpr size_t RBOFF = 25165824;   // rel bf16 [1025][64]
static constexpr size_t XBOFF = 25231424;   // X bf16 [16384][512]
static constexpr size_t WTOFF = 33620032;   // Wqkv^T bf16 [1536][512]
static constexpr size_t WOTOFF = 34406464;  // Wout^T bf16 [512][512]
static constexpr size_t OBOFF = 34668608;   // O bf16 [16384][512]

__device__ inline unsigned short f2b(float f) {  // RNE fp32->bf16
  unsigned int u = __float_as_uint(f);
  u += 0x7fffu + ((u >> 16) & 1u);
  return (unsigned short)(u >> 16);
}

// ---------------------------------------------------------------------------
// Converters
// ---------------------------------------------------------------------------
__global__ void rel_cvt(const float* __restrict__ rel, unsigned short* __restrict__ dst) {
  int i = blockIdx.x * 256 + threadIdx.x;
  if (i < 65600) dst[i] = f2b(rel[i]);
}

__global__ __launch_bounds__(256) void x_cvt(const float* __restrict__ in,
                                             unsigned short* __restrict__ dst) {
  size_t i8 = ((size_t)blockIdx.x * 256 + threadIdx.x) * 8;
  float4 a = *(const float4*)(in + i8);
  float4 b = *(const float4*)(in + i8 + 4);
  unsigned short t[8] = {f2b(a.x), f2b(a.y), f2b(a.z), f2b(a.w),
                         f2b(b.x), f2b(b.y), f2b(b.z), f2b(b.w)};
  *(uint4*)(dst + i8) = *(uint4*)t;
}

// transpose+convert: in fp32 [R][C] -> out bf16 [C][R]; grid (C/64, R/64)
__global__ __launch_bounds__(256) void t_cvt(const float* __restrict__ in,
                                             unsigned short* __restrict__ out,
                                             int R, int C) {
  __shared__ float T[64 * 65];
  const int tid = threadIdx.x;
  const int c0 = blockIdx.x * 64, r0 = blockIdx.y * 64;
#pragma unroll
  for (int p = 0; p < 4; ++p) {
    int r = (tid >> 4) + p * 16, c4 = (tid & 15) * 4;
    float4 v = *(const float4*)(in + (size_t)(r0 + r) * C + c0 + c4);
    T[r * 65 + c4 + 0] = v.x;
    T[r * 65 + c4 + 1] = v.y;
    T[r * 65 + c4 + 2] = v.z;
    T[r * 65 + c4 + 3] = v.w;
  }
  __syncthreads();
#pragma unroll
  for (int p = 0; p < 4; ++p) {
    int oc = (tid >> 4) + p * 16;
    int or4 = (tid & 15) * 4;
    unsigned short t[4];
#pragma unroll
    for (int j = 0; j < 4; ++j) t[j] = f2b(T[(or4 + j) * 65 + oc]);
    *(uint2*)(out + (size_t)(c0 + oc) * R + r0 + or4) = *(uint2*)t;
  }
}

// ---------------------------------------------------------------------------
// Kernel 1: qkv = Xb @ Wt^T (bf16 MFMA), scatter to Q(scaled)/K [n][d], V^T [d][n]
// ---------------------------------------------------------------------------
__global__ __launch_bounds__(256) void qkv_mfma(const unsigned short* __restrict__ Xb,
                                                const unsigned short* __restrict__ Wt,
                                                unsigned short* __restrict__ wsb) {
  __shared__ __align__(16) unsigned short As[128 * 40];
  __shared__ __align__(16) unsigned short Bs[128 * 40];
  const int tid = threadIdx.x;
  const int w = tid >> 6, lane = tid & 63;
  const int g = lane >> 4, c = lane & 15;
  const int m0 = blockIdx.x * 128, n0 = blockIdx.y * 128;
  const int wr = (w >> 1) * 64, wc = (w & 1) * 64;
  const bool vmode = (blockIdx.y >= 8);

  floatx4 acc[4][4];
#pragma unroll
  for (int mi = 0; mi < 4; ++mi)
#pragma unroll
    for (int ni = 0; ni < 4; ++ni) acc[mi][ni] = (floatx4){0.f, 0.f, 0.f, 0.f};

  for (int kk = 0; kk < 512; kk += 32) {
    __syncthreads();
#pragma unroll
    for (int p = 0; p < 2; ++p) {
      int e = tid + 256 * p;
      int r = e >> 2, o = e & 3;
      *(uint4*)(As + r * 40 + o * 8) = *(const uint4*)(Xb + (size_t)(m0 + r) * 512 + kk + o * 8);
      *(uint4*)(Bs + r * 40 + o * 8) = *(const uint4*)(Wt + (size_t)(n0 + r) * 512 + kk + o * 8);
    }
    __syncthreads();
    short8 a[4], b[4];
#pragma unroll
    for (int mi = 0; mi < 4; ++mi) a[mi] = *(const short8*)(As + (wr + mi * 16 + c) * 40 + g * 8);
#pragma unroll
    for (int ni = 0; ni < 4; ++ni) b[ni] = *(const short8*)(Bs + (wc + ni * 16 + c) * 40 + g * 8);
    if (vmode) {
#pragma unroll
      for (int mi = 0; mi < 4; ++mi)
#pragma unroll
        for (int ni = 0; ni < 4; ++ni)
          acc[mi][ni] = __builtin_amdgcn_mfma_f32_16x16x32_bf16(b[ni], a[mi], acc[mi][ni], 0, 0, 0);
    } else {
#pragma unroll
      for (int mi = 0; mi < 4; ++mi)
#pragma unroll
        for (int ni = 0; ni < 4; ++ni)
          acc[mi][ni] = __builtin_amdgcn_mfma_f32_16x16x32_bf16(a[mi], b[ni], acc[mi][ni], 0, 0, 0);
    }
  }

  constexpr float SCL = 0.125f * 1.44269504088896340736f;  // scale*log2e (Q only)
  if (vmode) {
#pragma unroll
    for (int mi = 0; mi < 4; ++mi) {
      const int xrow = m0 + wr + mi * 16 + c;
      const int bb = xrow >> 9, nn = xrow & 511;
#pragma unroll
      for (int ni = 0; ni < 4; ++ni) {
#pragma unroll
        for (int r = 0; r < 4; ++r) {
          const int C = n0 + wc + ni * 16 + g * 4 + r;
          const int col512 = C & 511;
          const int h = col512 >> 6, d = col512 & 63;
          wsb[VTOFF + (size_t)(bb * 8 + h) * 32768 + (size_t)d * 512 + nn] = f2b(acc[mi][ni][r]);
        }
      }
    }
  } else {
    const size_t base = (blockIdx.y >= 4) ? KOFF : QOFF;
    const float scl = (blockIdx.y >= 4) ? 1.0f : SCL;
#pragma unroll
    for (int ni = 0; ni < 4; ++ni) {
      const int C = n0 + wc + ni * 16 + c;
      const int col512 = C & 511;
      const int h = col512 >> 6, d = col512 & 63;
#pragma unroll
      for (int mi = 0; mi < 4; ++mi) {
#pragma unroll
        for (int r = 0; r < 4; ++r) {
          const int xrow = m0 + wr + mi * 16 + g * 4 + r;
          wsb[base + (size_t)((xrow >> 9) * 8 + h) * 32768 + (size_t)(xrow & 511) * 64 + d] =
              f2b(acc[mi][ni][r] * scl);
        }
      }
    }
  }
}

// ---------------------------------------------------------------------------
// Kernel 2: MFMA flash attention, swapped-operand form.
// S' = mfma(K-frag, Q-frag) -> D[j][i]; G' = mfma(T-frag, Q-frag) -> D[delta][i]
// Gs natural [i][delta] fp32 (b128 writes, b32 gathers); Ps natural [i][j]
// (b64 writes, b128 A-frag reads); Q/T frags straight from global (L2).
// LDS 52 KB -> 3 blocks/CU.
// ---------------------------------------------------------------------------
__global__ __launch_bounds__(256) void attn_mfma(const unsigned short* __restrict__ wsb,
                                                 unsigned short* __restrict__ Ob) {
  __shared__ __align__(16) unsigned short Ks[64 * 72];
  __shared__ __align__(16) unsigned short Vt[64 * 72];
  __shared__ __align__(16) unsigned short Ps[64 * 72];
  __shared__ __align__(16) float Gs[4 * 16 * 100];  // per-wave [i=16][delta'=100]

  const int tid = threadIdx.x;
  const int w = tid >> 6, lane = tid & 63;
  const int g = lane >> 4, c = lane & 15;
  const int i0 = blockIdx.x * 64, bh = blockIdx.y;

  const unsigned short* Qg = wsb + QOFF + (size_t)bh * 32768 + (size_t)i0 * 64;
  const unsigned short* Kg = wsb + KOFF + (size_t)bh * 32768;
  const unsigned short* Vg = wsb + VTOFF + (size_t)bh * 32768;
  const unsigned short* Rg = wsb + RBOFF;

  // Q fragments (B-operand: rows i = i0 + w*16 + c), hoisted across chunks
  const short8 bq0 = *(const short8*)(Qg + (size_t)(w * 16 + c) * 64 + g * 8);
  const short8 bq1 = *(const short8*)(Qg + (size_t)(w * 16 + c) * 64 + 32 + g * 8);

  float* GsW = Gs + w * 1600;
  unsigned short* PsW = Ps + (w * 16 + c) * 72;

  float m_i = -1e30f, l_i = 0.f;
  floatx4 oa[4];
#pragma unroll
  for (int t = 0; t < 4; ++t) oa[t] = (floatx4){0.f, 0.f, 0.f, 0.f};

  for (int jc = 0; jc < 8; ++jc) {
    const int j0 = jc * 64;
    __syncthreads();  // prior chunk's Ks/Vt reads done
    for (int e = tid; e < 512; e += 256) {
      int r = e >> 3, o = e & 7;
      *(uint4*)(Ks + r * 72 + o * 8) = *(const uint4*)(Kg + (size_t)(j0 + r) * 64 + o * 8);
      *(uint4*)(Vt + r * 72 + o * 8) = *(const uint4*)(Vg + (size_t)r * 512 + j0 + o * 8);
    }
    __syncthreads();  // staging visible

    // G' = rel-window @ Q^T for this wave's i-strip; window rows start at
    // delta = dbase + 16w (wave needs deltaloc' in [0,78])
    const int dbase = i0 - j0 + 449 + w * 16;
    const unsigned short* Trow = Rg + (size_t)dbase * 64 + (size_t)c * 64;
#pragma unroll
    for (int dd = 0; dd < 6; ++dd) {
      short8 t0 = *(const short8*)(Trow + dd * 1024 + g * 8);
      short8 t1 = *(const short8*)(Trow + dd * 1024 + 32 + g * 8);
      floatx4 ga = (floatx4){0.f, 0.f, 0.f, 0.f};
      ga = __builtin_amdgcn_mfma_f32_16x16x32_bf16(t0, bq0, ga, 0, 0, 0);
      ga = __builtin_amdgcn_mfma_f32_16x16x32_bf16(t1, bq1, ga, 0, 0, 0);
      *(floatx4*)(GsW + c * 100 + dd * 16 + 4 * g) = ga;  // natural [i=c][delta']
    }

    // S' = K @ Q^T : D[m=j][n=i]; lane (g,c): j = 16t+4g+r, i = c
    floatx4 s4[4];
#pragma unroll
    for (int t = 0; t < 4; ++t) {
      short8 k0 = *(const short8*)(Ks + (t * 16 + c) * 72 + g * 8);
      short8 k1 = *(const short8*)(Ks + (t * 16 + c) * 72 + 32 + g * 8);
      floatx4 sa = (floatx4){0.f, 0.f, 0.f, 0.f};
      sa = __builtin_amdgcn_mfma_f32_16x16x32_bf16(k0, bq0, sa, 0, 0, 0);
      sa = __builtin_amdgcn_mfma_f32_16x16x32_bf16(k1, bq1, sa, 0, 0, 0);
      s4[t] = sa;
    }

    // Toeplitz bias gather: delta' = c - j + 63  (in [0,78])
    const float* Grow = GsW + c * 100 + c + 63;
#pragma unroll
    for (int t = 0; t < 4; ++t)
#pragma unroll
      for (int r = 0; r < 4; ++r) s4[t][r] += Grow[-(16 * t + 4 * g + r)];

    // online softmax (base-2): one row (i = c) per lane, replicated over g
    float mx = -1e30f;
#pragma unroll
    for (int t = 0; t < 4; ++t)
      mx = fmaxf(mx, fmaxf(fmaxf(s4[t][0], s4[t][1]), fmaxf(s4[t][2], s4[t][3])));
    mx = fmaxf(mx, __shfl_xor(mx, 16));
    mx = fmaxf(mx, __shfl_xor(mx, 32));
    const float mn = fmaxf(m_i, mx);
    const float al = exp2f(m_i - mn);
    m_i = mn;
    float ls = 0.f;
#pragma unroll
    for (int t = 0; t < 4; ++t)
#pragma unroll
      for (int r = 0; r < 4; ++r) {
        float p = exp2f(s4[t][r] - mn);
        s4[t][r] = p;
        ls += p;
      }
    ls += __shfl_xor(ls, 16);
    ls += __shfl_xor(ls, 32);
    l_i = l_i * al + ls;

    // rescale O: O rows are i-local = 4g+r -> broadcast alpha from lane 4g+r
#pragma unroll
    for (int r = 0; r < 4; ++r) {
      const float ar = __shfl(al, 4 * g + r);
#pragma unroll
      for (int dt = 0; dt < 4; ++dt) oa[dt][r] *= ar;
    }

    // P store: natural [i=c][j], 4 consecutive j per register quad -> b64
#pragma unroll
    for (int t = 0; t < 4; ++t) {
      unsigned short pk[4] = {f2b(s4[t][0]), f2b(s4[t][1]), f2b(s4[t][2]), f2b(s4[t][3])};
      *(uint2*)(PsW + t * 16 + 4 * g) = *(uint2*)pk;
    }

    // PV: A = P[i][j] (rows i=c), B = V^T[d][j] (rows d)
    short8 ap0 = *(const short8*)(PsW + g * 8);
    short8 ap1 = *(const short8*)(PsW + 32 + g * 8);
#pragma unroll
    for (int dt = 0; dt < 4; ++dt) {
      short8 bv0 = *(const short8*)(Vt + (dt * 16 + c) * 72 + g * 8);
      short8 bv1 = *(const short8*)(Vt + (dt * 16 + c) * 72 + 32 + g * 8);
      oa[dt] = __builtin_amdgcn_mfma_f32_16x16x32_bf16(ap0, bv0, oa[dt], 0, 0, 0);
      oa[dt] = __builtin_amdgcn_mfma_f32_16x16x32_bf16(ap1, bv1, oa[dt], 0, 0, 0);
    }
  }

  // epilogue: O rows i = i0 + w*16 + 4g + r, col d = 16dt + c; 1/l from lane 4g+r
  const int b = bh >> 3, h = bh & 7;
  const float invl = 1.0f / l_i;
#pragma unroll
  for (int r = 0; r < 4; ++r) {
    const float inv = __shfl(invl, 4 * g + r);
    const int i = i0 + w * 16 + 4 * g + r;
    const size_t rowoff = ((size_t)(b * 512 + i)) * 512 + h * 64;
#pragma unroll
    for (int dt = 0; dt < 4; ++dt) Ob[rowoff + dt * 16 + c] = f2b(oa[dt][r] * inv);
  }
}

// ---------------------------------------------------------------------------
// Kernel 3: out = Ob[16384x512] @ WoT^T + bias (bf16 MFMA, fp32 out)
// ---------------------------------------------------------------------------
__global__ __launch_bounds__(256) void out_mfma(const unsigned short* __restrict__ Ab,
                                                const unsigned short* __restrict__ Bt,
                                                const float* __restrict__ bias,
                                                float* __restrict__ out) {
  __shared__ __align__(16) unsigned short As[128 * 40];
  __shared__ __align__(16) unsigned short Bs[128 * 40];
  const int tid = threadIdx.x;
  const int w = tid >> 6, lane = tid & 63;
  const int g = lane >> 4, c = lane & 15;
  const int m0 = blockIdx.x * 128, n0 = blockIdx.y * 128;
  const int wr = (w >> 1) * 64, wc = (w & 1) * 64;

  floatx4 acc[4][4];
#pragma unroll
  for (int mi = 0; mi < 4; ++mi)
#pragma unroll
    for (int ni = 0; ni < 4; ++ni) acc[mi][ni] = (floatx4){0.f, 0.f, 0.f, 0.f};

  for (int kk = 0; kk < 512; kk += 32) {
    __syncthreads();
#pragma unroll
    for (int p = 0; p < 2; ++p) {
      int e = tid + 256 * p;
      int r = e >> 2, o = e & 3;
      *(uint4*)(As + r * 40 + o * 8) = *(const uint4*)(Ab + (size_t)(m0 + r) * 512 + kk + o * 8);
      *(uint4*)(Bs + r * 40 + o * 8) = *(const uint4*)(Bt + (size_t)(n0 + r) * 512 + kk + o * 8);
    }
    __syncthreads();
    short8 a[4], b[4];
#pragma unroll
    for (int mi = 0; mi < 4; ++mi) a[mi] = *(const short8*)(As + (wr + mi * 16 + c) * 40 + g * 8);
#pragma unroll
    for (int ni = 0; ni < 4; ++ni) b[ni] = *(const short8*)(Bs + (wc + ni * 16 + c) * 40 + g * 8);
#pragma unroll
    for (int mi = 0; mi < 4; ++mi)
#pragma unroll
      for (int ni = 0; ni < 4; ++ni)
        acc[mi][ni] = __builtin_amdgcn_mfma_f32_16x16x32_bf16(a[mi], b[ni], acc[mi][ni], 0, 0, 0);
  }

#pragma unroll
  for (int ni = 0; ni < 4; ++ni) {
    const int C = n0 + wc + ni * 16 + c;
    const float bv = bias[C];
#pragma unroll
    for (int mi = 0; mi < 4; ++mi) {
#pragma unroll
      for (int r = 0; r < 4; ++r) {
        const int m = m0 + wr + mi * 16 + g * 4 + r;
        out[(size_t)m * 512 + C] = acc[mi][ni][r] + bv;
      }
    }
  }
}

// ---------------------------------------------------------------------------
extern "C" void kernel_launch(void* const* d_in, const int* in_sizes, int n_in,
                              void* d_out, int out_size, void* d_ws, size_t ws_size,
                              hipStream_t stream) {
  const float* x = (const float*)d_in[0];      // [32,512,512]
  const float* Wqkv = (const float*)d_in[1];   // [512,1536]
  const float* rel = (const float*)d_in[2];    // [1025,64]
  const float* Wout = (const float*)d_in[3];   // [512,512]
  const float* bout = (const float*)d_in[4];   // [512]
  float* out = (float*)d_out;
  unsigned short* wsb = (unsigned short*)d_ws;

  rel_cvt<<<257, 256, 0, stream>>>(rel, wsb + RBOFF);
  x_cvt<<<4096, 256, 0, stream>>>(x, wsb + XBOFF);
  t_cvt<<<dim3(24, 8), 256, 0, stream>>>(Wqkv, wsb + WTOFF, 512, 1536);
  t_cvt<<<dim3(8, 8), 256, 0, stream>>>(Wout, wsb + WOTOFF, 512, 512);
  qkv_mfma<<<dim3(128, 12), 256, 0, stream>>>(wsb + XBOFF, wsb + WTOFF, wsb);
  attn_mfma<<<dim3(8, 256), 256, 0, stream>>>(wsb, wsb + OBOFF);
  out_mfma<<<dim3(128, 4), 256, 0, stream>>>(wsb + OBOFF, wsb + WOTOFF, bout, out);
}